// Round 9
// baseline (187.829 us; speedup 1.0000x reference)
//
#include <hip/hip_runtime.h>
#include <math.h>

#define VOCAB   50265
#define D       768
#define N_NEW   200
#define N_NODES 199
#define N_EDGES 1024
#define LEAKY   0.2f

typedef float f4 __attribute__((ext_vector_type(4)));

// ---- GEMM split-K config ----
#define ROW_T 4
#define KC    16
#define KLEN  48                  // 768/KC
#define NROWT 50                  // ceil(199/4)
#define NCH   (KC * 3)            // svp/dvp slots per row (48)
// partial[kc][row][col]  (KC * 199 * 768 floats)
// svp/dvp[row][kc*3+colt] (199 * 48 floats)

// ---------------- Kernel 1: split-K GEMM partials + split partial dots
__global__ __launch_bounds__(256) void gemm_partial_kernel(
    const float* __restrict__ new_emb, const float* __restrict__ W,
    const float* __restrict__ a_src, const float* __restrict__ a_dst,
    float* __restrict__ partial, float* __restrict__ svp, float* __restrict__ dvp)
{
    __shared__ float fts[ROW_T][KLEN];       // 768 B
    __shared__ float rS[ROW_T][4], rD[ROW_T][4];
    const int tid  = threadIdx.x;
    const int rowt = blockIdx.x;
    const int colt = blockIdx.y;
    const int kc   = blockIdx.z;
    const int row0 = rowt * ROW_T;
    const int col  = colt * 256 + tid;
    const int k0   = kc * KLEN;
    const int lane = tid & 63, wid = tid >> 6;

    for (int i = tid; i < ROW_T * KLEN; i += 256) {
        int r  = i / KLEN;
        int kk = i - r * KLEN;
        int row = row0 + r;
        fts[r][kk] = (row < N_NODES) ? new_emb[(size_t)(1 + row) * D + k0 + kk] : 0.f;
    }
    __syncthreads();

    float acc[ROW_T] = {0.f, 0.f, 0.f, 0.f};
    #pragma unroll 6
    for (int kk = 0; kk < KLEN; ++kk) {
        float w = W[(size_t)(k0 + kk) * D + col];
        #pragma unroll
        for (int r = 0; r < ROW_T; ++r)
            acc[r] = fmaf(fts[r][kk], w, acc[r]);
    }

    const size_t base = ((size_t)kc * N_NODES) * D + col;
    #pragma unroll
    for (int r = 0; r < ROW_T; ++r)
        if (row0 + r < N_NODES) partial[base + (size_t)(row0 + r) * D] = acc[r];

    // split partial dots: this block's 256-col slice of h[row].a_src/.a_dst
    const float as = a_src[col];
    const float ad = a_dst[col];
    #pragma unroll
    for (int r = 0; r < ROW_T; ++r) {
        float ps = acc[r] * as;
        float pd = acc[r] * ad;
        #pragma unroll
        for (int off = 32; off; off >>= 1) {
            ps += __shfl_down(ps, off, 64);
            pd += __shfl_down(pd, off, 64);
        }
        if (lane == 0) { rS[r][wid] = ps; rD[r][wid] = pd; }
    }
    __syncthreads();
    if (tid < ROW_T) {
        const int row = row0 + tid;
        if (row < N_NODES) {
            const int slot = row * NCH + kc * 3 + colt;
            svp[slot] = rS[tid][0] + rS[tid][1] + rS[tid][2] + rS[tid][3];
            dvp[slot] = rD[tid][0] + rD[tid][1] + rD[tid][2] + rD[tid][3];
        }
    }
}

// ---------------- Kernel 2: persistent gather with fused GAT finish
#define GATHER_BLOCKS 2048

__global__ __launch_bounds__(256) void gather_fused_kernel(
    const int* __restrict__ x, const float* __restrict__ orig_emb,
    const float* __restrict__ new_emb, const int* __restrict__ edge_index,
    const float* __restrict__ partial, const float* __restrict__ svp,
    const float* __restrict__ dvp, float* __restrict__ out, int ntok)
{
    __shared__ int mlist[4][32];
    const int tid  = threadIdx.x;
    const int lane = tid & 63;
    const int wid  = tid >> 6;
    const int step = GATHER_BLOCKS * 4;

    for (int token = blockIdx.x * 4 + wid; token < ntok; token += step) {
        const int idx = x[token];
        f4* dst = (f4*)(out + (size_t)token * D);

        if (idx < VOCAB) {
            const f4* src = (const f4*)(orig_emb + (size_t)idx * D);
            f4 v0 = src[lane];
            f4 v1 = src[lane + 64];
            f4 v2 = src[lane + 128];
            __builtin_nontemporal_store(v0, &dst[lane]);
            __builtin_nontemporal_store(v1, &dst[lane + 64]);
            __builtin_nontemporal_store(v2, &dst[lane + 128]);
            continue;
        }
        if (idx >= VOCAB + N_NODES) {
            const f4* src = (const f4*)(new_emb + (size_t)N_NEW * D);
            f4 v0 = src[lane];
            f4 v1 = src[lane + 64];
            f4 v2 = src[lane + 128];
            __builtin_nontemporal_store(v0, &dst[lane]);
            __builtin_nontemporal_store(v1, &dst[lane + 64]);
            __builtin_nontemporal_store(v2, &dst[lane + 128]);
            continue;
        }

        // ---- graph token: node n ----
        const int n = idx - VOCAB;

        // 1) scan dst list for in-edges of n (deterministic order)
        int cnt = 0;
        for (int j = 0; j < 4; ++j) {
            const int4 d4 = ((const int4*)(edge_index + N_EDGES))[j * 64 + lane];
            const int dd[4] = { d4.x, d4.y, d4.z, d4.w };
            #pragma unroll
            for (int i = 0; i < 4; ++i) {
                const unsigned long long mask = __ballot(dd[i] == n);
                if (dd[i] == n) {
                    int pos = cnt + __popcll(mask & ((1ull << lane) - 1ull));
                    if (pos < 32) mlist[wid][pos] = j * 256 + lane * 4 + i;
                }
                cnt += __popcll(mask);
            }
        }
        const int c = min(cnt, 32);

        f4 acc0 = {0.f, 0.f, 0.f, 0.f};
        f4 acc1 = {0.f, 0.f, 0.f, 0.f};
        f4 acc2 = {0.f, 0.f, 0.f, 0.f};

        if (c > 0) {
            // 2) dv[n]
            float dvn = 0.f;
            #pragma unroll
            for (int q = 0; q < NCH; ++q) dvn += dvp[n * NCH + q];

            // 3) per-lane edge scores
            float e = -INFINITY;
            int   srcp = 0;
            if (lane < c) {
                const int k = mlist[wid][lane];
                srcp = edge_index[k];
                float sv = 0.f;
                #pragma unroll
                for (int q = 0; q < NCH; ++q) sv += svp[srcp * NCH + q];
                const float ev = sv + dvn;
                e = ev > 0.f ? ev : LEAKY * ev;
            }
            float m = e;
            #pragma unroll
            for (int off = 32; off; off >>= 1)
                m = fmaxf(m, __shfl_xor(m, off, 64));
            float ex = (lane < c) ? expf(e - m) : 0.f;
            float dn = ex;
            #pragma unroll
            for (int off = 32; off; off >>= 1)
                dn += __shfl_xor(dn, off, 64);
            const float alpha = ex / fmaxf(dn, 1e-9f);

            // 4) aggregate: acc += alpha_p * h[src_p], h summed from KC chunks
            const int kstr = N_NODES * D / 4;     // f4 stride between kc chunks
            for (int p = 0; p < c; ++p) {
                const float a = __shfl(alpha, p, 64);
                const int   s = __shfl(srcp,  p, 64);
                const f4* pb = (const f4*)(partial + (size_t)s * D);
                #pragma unroll
                for (int ch = 0; ch < 3; ++ch) {
                    const int o = ch * 64 + lane;
                    f4 hsum = {0.f, 0.f, 0.f, 0.f};
                    #pragma unroll
                    for (int q = 0; q < KC; ++q)
                        hsum += pb[o + q * kstr];
                    f4* ac = (ch == 0) ? &acc0 : (ch == 1) ? &acc1 : &acc2;
                    *ac += a * hsum;
                }
            }
        }

        // 5) elu + residual, store
        const f4* f4p = (const f4*)(new_emb + (size_t)(1 + n) * D);
        f4 accs[3] = {acc0, acc1, acc2};
        #pragma unroll
        for (int ch = 0; ch < 3; ++ch) {
            const int o = ch * 64 + lane;
            const f4 r = f4p[o];
            f4 v;
            v.x = (accs[ch].x > 0.f ? accs[ch].x : expf(accs[ch].x) - 1.f) + r.x;
            v.y = (accs[ch].y > 0.f ? accs[ch].y : expf(accs[ch].y) - 1.f) + r.y;
            v.z = (accs[ch].z > 0.f ? accs[ch].z : expf(accs[ch].z) - 1.f) + r.z;
            v.w = (accs[ch].w > 0.f ? accs[ch].w : expf(accs[ch].w) - 1.f) + r.w;
            __builtin_nontemporal_store(v, &dst[o]);
        }
    }
}

extern "C" void kernel_launch(void* const* d_in, const int* in_sizes, int n_in,
                              void* d_out, int out_size, void* d_ws, size_t ws_size,
                              hipStream_t stream) {
    const int*   x        = (const int*)  d_in[0];
    const float* orig_emb = (const float*)d_in[1];
    const float* new_emb  = (const float*)d_in[2];
    const float* W        = (const float*)d_in[3];
    const float* a_src    = (const float*)d_in[4];
    const float* a_dst    = (const float*)d_in[5];
    const int*   edge_idx = (const int*)  d_in[6];
    float* out = (float*)d_out;

    // workspace layout (floats) — everything written before read
    float* ws      = (float*)d_ws;
    float* partial = ws;                                   // KC*199*768
    float* svp     = partial + (size_t)KC * N_NODES * D;   // 199*NCH
    float* dvp     = svp + N_NODES * NCH;                  // 199*NCH

    const int ntok = in_sizes[0];                          // 32768

    gemm_partial_kernel<<<dim3(NROWT, 3, KC), 256, 0, stream>>>(
        new_emb, W, a_src, a_dst, partial, svp, dvp);
    gather_fused_kernel<<<GATHER_BLOCKS, 256, 0, stream>>>(
        x, orig_emb, new_emb, edge_idx, partial, svp, dvp, out, ntok);
}

// Round 10
// 59.755 us; speedup vs baseline: 3.1433x; 3.1433x over previous
//
#include <hip/hip_runtime.h>
#include <math.h>

#define VOCAB   50265
#define D       768
#define N_NEW   200
#define N_NODES 199
#define N_EDGES 1024
#define LEAKY   0.2f

typedef float f4 __attribute__((ext_vector_type(4)));

// ---- GEMM split-K config ----
#define ROW_T 4
#define KC    8
#define KLEN  96                  // 768/KC
#define NROWT 50                  // ceil(199/4)
#define NCH   (KC * 3)            // svp/dvp slots per row (24)

// ---------------- Kernel 1: split-K GEMM partials + split partial dots
__global__ __launch_bounds__(256) void gemm_partial_kernel(
    const float* __restrict__ new_emb, const float* __restrict__ W,
    const float* __restrict__ a_src, const float* __restrict__ a_dst,
    float* __restrict__ partial, float* __restrict__ svp, float* __restrict__ dvp)
{
    __shared__ float fts[ROW_T][KLEN];
    __shared__ float rS[ROW_T][4], rD[ROW_T][4];
    const int tid  = threadIdx.x;
    const int rowt = blockIdx.x;
    const int colt = blockIdx.y;
    const int kc   = blockIdx.z;
    const int row0 = rowt * ROW_T;
    const int col  = colt * 256 + tid;
    const int k0   = kc * KLEN;
    const int lane = tid & 63, wid = tid >> 6;

    for (int i = tid; i < ROW_T * KLEN; i += 256) {
        int r  = i / KLEN;
        int kk = i - r * KLEN;
        int row = row0 + r;
        fts[r][kk] = (row < N_NODES) ? new_emb[(size_t)(1 + row) * D + k0 + kk] : 0.f;
    }
    __syncthreads();

    float acc[ROW_T] = {0.f, 0.f, 0.f, 0.f};
    #pragma unroll 4
    for (int kk = 0; kk < KLEN; ++kk) {
        float w = W[(size_t)(k0 + kk) * D + col];
        #pragma unroll
        for (int r = 0; r < ROW_T; ++r)
            acc[r] = fmaf(fts[r][kk], w, acc[r]);
    }

    const size_t base = ((size_t)kc * N_NODES) * D + col;
    #pragma unroll
    for (int r = 0; r < ROW_T; ++r)
        if (row0 + r < N_NODES) partial[base + (size_t)(row0 + r) * D] = acc[r];

    const float as = a_src[col];
    const float ad = a_dst[col];
    #pragma unroll
    for (int r = 0; r < ROW_T; ++r) {
        float ps = acc[r] * as;
        float pd = acc[r] * ad;
        #pragma unroll
        for (int off = 32; off; off >>= 1) {
            ps += __shfl_down(ps, off, 64);
            pd += __shfl_down(pd, off, 64);
        }
        if (lane == 0) { rS[r][wid] = ps; rD[r][wid] = pd; }
    }
    __syncthreads();
    if (tid < ROW_T) {
        const int row = row0 + tid;
        if (row < N_NODES) {
            const int slot = row * NCH + kc * 3 + colt;
            svp[slot] = rS[tid][0] + rS[tid][1] + rS[tid][2] + rS[tid][3];
            dvp[slot] = rD[tid][0] + rD[tid][1] + rD[tid][2] + rD[tid][3];
        }
    }
}

// ---------------- Kernel 2: per-node softmax + aggregate (one block per node)
// Reads h on the fly as the KC-chunk sum of `partial` — no inter-block deps.
__global__ __launch_bounds__(256) void softagg_kernel(
    const int* __restrict__ edge_index, const float* __restrict__ svp,
    const float* __restrict__ dvp, const float* __restrict__ partial,
    const float* __restrict__ new_emb, float* __restrict__ gfeats)
{
    __shared__ float sv_l[N_NODES], dv_l[N_NODES];
    __shared__ float e[N_EDGES];
    __shared__ short ssrc[N_EDGES];
    __shared__ short ml[N_EDGES];
    __shared__ int   wsum[4];
    __shared__ int   s_total;
    const int n   = blockIdx.x;
    const int tid = threadIdx.x;
    const int lane = tid & 63, wid = tid >> 6;

    for (int i = tid; i < N_NODES; i += 256) {
        float s = 0.f, d = 0.f;
        #pragma unroll
        for (int q = 0; q < NCH; ++q) {
            s += svp[i * NCH + q];
            d += dvp[i * NCH + q];
        }
        sv_l[i] = s;
        dv_l[i] = d;
    }
    __syncthreads();

    // thread t owns edges [4t, 4t+4)
    const int4 se = ((const int4*)edge_index)[tid];
    const int4 de = ((const int4*)(edge_index + N_EDGES))[tid];
    const int srcs[4] = { se.x, se.y, se.z, se.w };
    const int dsts[4] = { de.x, de.y, de.z, de.w };

    int mycnt = 0;
    #pragma unroll
    for (int j = 0; j < 4; ++j) {
        const int k = 4 * tid + j;
        float ev = sv_l[srcs[j]] + dv_l[dsts[j]];
        e[k] = ev > 0.f ? ev : LEAKY * ev;
        ssrc[k] = (short)srcs[j];
        if (dsts[j] == n) ++mycnt;
    }

    // exclusive prefix of mycnt over 256 threads
    int pre = mycnt;
    #pragma unroll
    for (int off = 1; off < 64; off <<= 1) {
        int v = __shfl_up(pre, off, 64);
        if (lane >= off) pre += v;
    }
    if (lane == 63) wsum[wid] = pre;
    __syncthreads();
    int woff = 0;
    for (int w = 0; w < wid; ++w) woff += wsum[w];
    int base = woff + pre - mycnt;
    #pragma unroll
    for (int j = 0; j < 4; ++j) {
        if (dsts[j] == n) ml[base++] = (short)(4 * tid + j);
    }
    if (tid == 255) s_total = woff + pre;
    __syncthreads();

    const int c = s_total;

    // redundant (deterministic) max/denom over this node's edges
    float mx = -INFINITY;
    for (int p = 0; p < c; ++p) mx = fmaxf(mx, e[ml[p]]);
    float dn = 0.f;
    for (int p = 0; p < c; ++p) dn += expf(e[ml[p]] - mx);
    const float inv = 1.f / fmaxf(dn, 1e-9f);

    // aggregate: thread handles cols tid, tid+256, tid+512
    const size_t kcstride = (size_t)N_NODES * D;
    float a0 = 0.f, a1 = 0.f, a2 = 0.f;
    for (int p = 0; p < c; ++p) {
        const int k = ml[p];
        const float a = expf(e[k] - mx) * inv;
        const float* pb = partial + (size_t)ssrc[k] * D;
        float h0 = 0.f, h1 = 0.f, h2 = 0.f;
        #pragma unroll
        for (int q = 0; q < KC; ++q) {
            h0 += pb[q * kcstride + tid];
            h1 += pb[q * kcstride + tid + 256];
            h2 += pb[q * kcstride + tid + 512];
        }
        a0 = fmaf(a, h0, a0);
        a1 = fmaf(a, h1, a1);
        a2 = fmaf(a, h2, a2);
    }
    const float* f = new_emb + (size_t)(1 + n) * D;
    float e0 = a0 > 0.f ? a0 : expf(a0) - 1.f;
    float e1 = a1 > 0.f ? a1 : expf(a1) - 1.f;
    float e2 = a2 > 0.f ? a2 : expf(a2) - 1.f;
    gfeats[(size_t)n * D + tid]       = e0 + f[tid];
    gfeats[(size_t)n * D + tid + 256] = e1 + f[tid + 256];
    gfeats[(size_t)n * D + tid + 512] = e2 + f[tid + 512];
}

// ---------------- Kernel 3: gather. One wave per token, uniform cost.
__global__ __launch_bounds__(256) void gather_kernel(
    const int* __restrict__ x, const float* __restrict__ orig_emb,
    const float* __restrict__ gfeats, const float* __restrict__ new_emb,
    float* __restrict__ out, int ntok)
{
    const int token = blockIdx.x * 4 + (threadIdx.x >> 6);
    if (token >= ntok) return;
    const int lane = threadIdx.x & 63;
    const int idx = x[token];

    const f4* src;
    if (idx < VOCAB)
        src = (const f4*)(orig_emb + (size_t)idx * D);
    else if (idx < VOCAB + N_NODES)
        src = (const f4*)(gfeats + (size_t)(idx - VOCAB) * D);
    else
        src = (const f4*)(new_emb + (size_t)N_NEW * D);

    f4* dst = (f4*)(out + (size_t)token * D);
    f4 v0 = src[lane];
    f4 v1 = src[lane + 64];
    f4 v2 = src[lane + 128];
    __builtin_nontemporal_store(v0, &dst[lane]);
    __builtin_nontemporal_store(v1, &dst[lane + 64]);
    __builtin_nontemporal_store(v2, &dst[lane + 128]);
}

extern "C" void kernel_launch(void* const* d_in, const int* in_sizes, int n_in,
                              void* d_out, int out_size, void* d_ws, size_t ws_size,
                              hipStream_t stream) {
    const int*   x        = (const int*)  d_in[0];
    const float* orig_emb = (const float*)d_in[1];
    const float* new_emb  = (const float*)d_in[2];
    const float* W        = (const float*)d_in[3];
    const float* a_src    = (const float*)d_in[4];
    const float* a_dst    = (const float*)d_in[5];
    const int*   edge_idx = (const int*)  d_in[6];
    float* out = (float*)d_out;

    // workspace layout (floats) — everything written before read
    float* ws      = (float*)d_ws;
    float* partial = ws;                                   // KC*199*768
    float* svp     = partial + (size_t)KC * N_NODES * D;   // 199*NCH
    float* dvp     = svp + N_NODES * NCH;                  // 199*NCH
    float* gfeats  = dvp + N_NODES * NCH;                  // 199*768

    const int ntok = in_sizes[0];                          // 32768

    gemm_partial_kernel<<<dim3(NROWT, 3, KC), 256, 0, stream>>>(
        new_emb, W, a_src, a_dst, partial, svp, dvp);
    softagg_kernel<<<N_NODES, 256, 0, stream>>>(
        edge_idx, svp, dvp, partial, new_emb, gfeats);
    gather_kernel<<<(ntok + 3) / 4, 256, 0, stream>>>(
        x, orig_emb, gfeats, new_emb, out, ntok);
}

// Round 11
// 56.882 us; speedup vs baseline: 3.3021x; 1.0505x over previous
//
#include <hip/hip_runtime.h>
#include <math.h>

#define VOCAB   50265
#define D       768
#define N_NEW   200
#define N_NODES 199
#define N_EDGES 1024
#define LEAKY   0.2f

typedef float f4 __attribute__((ext_vector_type(4)));

// ---- GEMM split-K config ----
#define ROW_T 4
#define KC    8
#define KLEN  96                  // 768/KC
#define NROWT 50                  // ceil(199/4)
#define NCH   (KC * 3)            // svp/dvp slots per row (24)
#define NB_GEMM (NROWT * 3 * KC)  // 1200

// ---------------- L1: hybrid — gemm blocks + gather blocks
__global__ __launch_bounds__(256) void hybrid_kernel(
    const int* __restrict__ x, const float* __restrict__ orig_emb,
    const float* __restrict__ new_emb, const float* __restrict__ W,
    const float* __restrict__ a_src, const float* __restrict__ a_dst,
    float* __restrict__ partial, float* __restrict__ svp, float* __restrict__ dvp,
    float* __restrict__ out, int* __restrict__ gcnt, int* __restrict__ glist,
    int ntok)
{
    const int tid = threadIdx.x;
    const int bid = blockIdx.x;

    if (bid < NB_GEMM) {
        // ================= GEMM partial =================
        __shared__ float fts[ROW_T][KLEN];
        __shared__ float rS[ROW_T][4], rD[ROW_T][4];
        const int rowt = bid % NROWT;
        const int colt = (bid / NROWT) % 3;
        const int kc   = bid / (NROWT * 3);
        const int row0 = rowt * ROW_T;
        const int col  = colt * 256 + tid;
        const int k0   = kc * KLEN;
        const int lane = tid & 63, wid = tid >> 6;

        for (int i = tid; i < ROW_T * KLEN; i += 256) {
            int r  = i / KLEN;
            int kk = i - r * KLEN;
            int row = row0 + r;
            fts[r][kk] = (row < N_NODES) ? new_emb[(size_t)(1 + row) * D + k0 + kk] : 0.f;
        }
        __syncthreads();

        float acc[ROW_T] = {0.f, 0.f, 0.f, 0.f};
        #pragma unroll 4
        for (int kk = 0; kk < KLEN; ++kk) {
            float w = W[(size_t)(k0 + kk) * D + col];
            #pragma unroll
            for (int r = 0; r < ROW_T; ++r)
                acc[r] = fmaf(fts[r][kk], w, acc[r]);
        }

        const size_t base = ((size_t)kc * N_NODES) * D + col;
        #pragma unroll
        for (int r = 0; r < ROW_T; ++r)
            if (row0 + r < N_NODES) partial[base + (size_t)(row0 + r) * D] = acc[r];

        const float as = a_src[col];
        const float ad = a_dst[col];
        #pragma unroll
        for (int r = 0; r < ROW_T; ++r) {
            float ps = acc[r] * as;
            float pd = acc[r] * ad;
            #pragma unroll
            for (int off = 32; off; off >>= 1) {
                ps += __shfl_down(ps, off, 64);
                pd += __shfl_down(pd, off, 64);
            }
            if (lane == 0) { rS[r][wid] = ps; rD[r][wid] = pd; }
        }
        __syncthreads();
        if (tid < ROW_T) {
            const int row = row0 + tid;
            if (row < N_NODES) {
                const int slot = row * NCH + kc * 3 + colt;
                svp[slot] = rS[tid][0] + rS[tid][1] + rS[tid][2] + rS[tid][3];
                dvp[slot] = rD[tid][0] + rD[tid][1] + rD[tid][2] + rD[tid][3];
            }
        }
        return;
    }

    // ================= Gather (non-graph tokens) =================
    const int token = (bid - NB_GEMM) * 4 + (tid >> 6);
    if (token >= ntok) return;
    const int lane = tid & 63;
    const int idx = x[token];

    if (idx >= VOCAB && idx < VOCAB + N_NODES) {
        // graph token: defer to fixup kernel
        if (lane == 0) {
            int pos = atomicAdd(gcnt, 1);
            glist[pos] = token;
        }
        return;
    }

    const f4* src = (idx < VOCAB)
        ? (const f4*)(orig_emb + (size_t)idx * D)
        : (const f4*)(new_emb + (size_t)N_NEW * D);

    f4* dst = (f4*)(out + (size_t)token * D);
    f4 v0 = src[lane];
    f4 v1 = src[lane + 64];
    f4 v2 = src[lane + 128];
    __builtin_nontemporal_store(v0, &dst[lane]);
    __builtin_nontemporal_store(v1, &dst[lane + 64]);
    __builtin_nontemporal_store(v2, &dst[lane + 128]);
}

// ---------------- L2: per-node softmax + aggregate (one block per node)
__global__ __launch_bounds__(256) void softagg_kernel(
    const int* __restrict__ edge_index, const float* __restrict__ svp,
    const float* __restrict__ dvp, const float* __restrict__ partial,
    const float* __restrict__ new_emb, float* __restrict__ gfeats)
{
    __shared__ float sv_l[N_NODES], dv_l[N_NODES];
    __shared__ float e[N_EDGES];
    __shared__ short ssrc[N_EDGES];
    __shared__ short ml[N_EDGES];
    __shared__ int   wsum[4];
    __shared__ int   s_total;
    const int n   = blockIdx.x;
    const int tid = threadIdx.x;
    const int lane = tid & 63, wid = tid >> 6;

    for (int i = tid; i < N_NODES; i += 256) {
        float s = 0.f, d = 0.f;
        #pragma unroll
        for (int q = 0; q < NCH; ++q) {
            s += svp[i * NCH + q];
            d += dvp[i * NCH + q];
        }
        sv_l[i] = s;
        dv_l[i] = d;
    }
    __syncthreads();

    const int4 se = ((const int4*)edge_index)[tid];
    const int4 de = ((const int4*)(edge_index + N_EDGES))[tid];
    const int srcs[4] = { se.x, se.y, se.z, se.w };
    const int dsts[4] = { de.x, de.y, de.z, de.w };

    int mycnt = 0;
    #pragma unroll
    for (int j = 0; j < 4; ++j) {
        const int k = 4 * tid + j;
        float ev = sv_l[srcs[j]] + dv_l[dsts[j]];
        e[k] = ev > 0.f ? ev : LEAKY * ev;
        ssrc[k] = (short)srcs[j];
        if (dsts[j] == n) ++mycnt;
    }

    int pre = mycnt;
    #pragma unroll
    for (int off = 1; off < 64; off <<= 1) {
        int v = __shfl_up(pre, off, 64);
        if (lane >= off) pre += v;
    }
    if (lane == 63) wsum[wid] = pre;
    __syncthreads();
    int woff = 0;
    for (int w = 0; w < wid; ++w) woff += wsum[w];
    int base = woff + pre - mycnt;
    #pragma unroll
    for (int j = 0; j < 4; ++j) {
        if (dsts[j] == n) ml[base++] = (short)(4 * tid + j);
    }
    if (tid == 255) s_total = woff + pre;
    __syncthreads();

    const int c = s_total;

    float mx = -INFINITY;
    for (int p = 0; p < c; ++p) mx = fmaxf(mx, e[ml[p]]);
    float dn = 0.f;
    for (int p = 0; p < c; ++p) dn += expf(e[ml[p]] - mx);
    const float inv = 1.f / fmaxf(dn, 1e-9f);

    const size_t kcstride = (size_t)N_NODES * D;
    float a0 = 0.f, a1 = 0.f, a2 = 0.f;
    for (int p = 0; p < c; ++p) {
        const int k = ml[p];
        const float a = expf(e[k] - mx) * inv;
        const float* pb = partial + (size_t)ssrc[k] * D;
        float h0 = 0.f, h1 = 0.f, h2 = 0.f;
        #pragma unroll
        for (int q = 0; q < KC; ++q) {
            h0 += pb[q * kcstride + tid];
            h1 += pb[q * kcstride + tid + 256];
            h2 += pb[q * kcstride + tid + 512];
        }
        a0 = fmaf(a, h0, a0);
        a1 = fmaf(a, h1, a1);
        a2 = fmaf(a, h2, a2);
    }
    const float* f = new_emb + (size_t)(1 + n) * D;
    float e0 = a0 > 0.f ? a0 : expf(a0) - 1.f;
    float e1 = a1 > 0.f ? a1 : expf(a1) - 1.f;
    float e2 = a2 > 0.f ? a2 : expf(a2) - 1.f;
    gfeats[(size_t)n * D + tid]       = e0 + f[tid];
    gfeats[(size_t)n * D + tid + 256] = e1 + f[tid + 256];
    gfeats[(size_t)n * D + tid + 512] = e2 + f[tid + 512];
}

// ---------------- L3: fixup — copy gfeats rows for recorded graph tokens
#define FIX_BLOCKS 64
__global__ __launch_bounds__(256) void fixup_kernel(
    const int* __restrict__ x, const float* __restrict__ gfeats,
    const int* __restrict__ gcnt, const int* __restrict__ glist,
    float* __restrict__ out)
{
    const int lane = threadIdx.x & 63;
    const int wid  = threadIdx.x >> 6;
    const int cnt  = *gcnt;

    for (int i = blockIdx.x * 4 + wid; i < cnt; i += FIX_BLOCKS * 4) {
        const int token = glist[i];
        const int n = x[token] - VOCAB;
        const f4* src = (const f4*)(gfeats + (size_t)n * D);
        f4* dst = (f4*)(out + (size_t)token * D);
        f4 v0 = src[lane];
        f4 v1 = src[lane + 64];
        f4 v2 = src[lane + 128];
        __builtin_nontemporal_store(v0, &dst[lane]);
        __builtin_nontemporal_store(v1, &dst[lane + 64]);
        __builtin_nontemporal_store(v2, &dst[lane + 128]);
    }
}

extern "C" void kernel_launch(void* const* d_in, const int* in_sizes, int n_in,
                              void* d_out, int out_size, void* d_ws, size_t ws_size,
                              hipStream_t stream) {
    const int*   x        = (const int*)  d_in[0];
    const float* orig_emb = (const float*)d_in[1];
    const float* new_emb  = (const float*)d_in[2];
    const float* W        = (const float*)d_in[3];
    const float* a_src    = (const float*)d_in[4];
    const float* a_dst    = (const float*)d_in[5];
    const int*   edge_idx = (const int*)  d_in[6];
    float* out = (float*)d_out;

    // workspace layout
    int*   gcnt    = (int*)d_ws;                               // [0] counter
    float* partial = (float*)((char*)d_ws + 256);              // KC*199*768
    float* svp     = partial + (size_t)KC * N_NODES * D;       // 199*NCH
    float* dvp     = svp + N_NODES * NCH;                      // 199*NCH
    float* gfeats  = dvp + N_NODES * NCH;                      // 199*768
    int*   glist   = (int*)(gfeats + (size_t)N_NODES * D);     // up to ntok

    const int ntok = in_sizes[0];                              // 32768
    const int nblocks = NB_GEMM + (ntok + 3) / 4;              // 1200 + 8192

    hipMemsetAsync(gcnt, 0, 16, stream);
    hybrid_kernel<<<nblocks, 256, 0, stream>>>(
        x, orig_emb, new_emb, W, a_src, a_dst,
        partial, svp, dvp, out, gcnt, glist, ntok);
    softagg_kernel<<<N_NODES, 256, 0, stream>>>(
        edge_idx, svp, dvp, partial, new_emb, gfeats);
    fixup_kernel<<<FIX_BLOCKS, 256, 0, stream>>>(
        x, gfeats, gcnt, glist, out);
}